// Round 15
// baseline (94.764 us; speedup 1.0000x reference)
//
#include <hip/hip_runtime.h>
#include <stdint.h>

#define KK 5
#define SCALE_F 50000.0f
#define OC 128
#define IC 128
#define HH 56
#define WW 56
#define NB 64
#define HWSZ (HH * WW)          // 3136
#define NTAP 9
#define NWEL (OC * IC * NTAP)   // 147456

// ---- MFMA path geometry ----
#define PD 58                   // padded spatial dim
#define NICQ 8                  // 16-byte ic-chunks per pixel (128 ic)
// apk8 chunk index: ((n*PD + hh)*NICQ + icq)*PD + ww ; byte addr = chunk*16
// bfrag chunk index: (kk*4 + oct)*64 + lane   (kk = icb*9 + tap)

// ---- bitplane fallback geometry (verified R5) ----
#define PW 60
#define PROWS 58
#define PLANE (PROWS * PW)      // 3480
#define PLSTRIDE (NB * PLANE)   // 222720
#define OCPB 2
#define WPT 4

typedef int v4i  __attribute__((ext_vector_type(4)));
typedef int v16i __attribute__((ext_vector_type(16)));

__device__ __forceinline__ constexpr int koff2(int kk) {
    int icb = kk / 9, tap = kk % 9;
    int dh = tap / 3 - 1, dw = tap % 3 - 1;
    return (dh * NICQ + icb * 2) * PD + dw;   // same formula for LDS A tile
}

// ===========================================================================
// ============================ MFMA (primary) path ==========================
// ===========================================================================

// Kernel 0: zero the padded borders of apk8 (1824 chunks per n).
__global__ void __launch_bounds__(256) border_kernel(int8_t* __restrict__ apk8) {
    int j = blockIdx.x * 256 + threadIdx.x;       // < 64*1824 = 116736
    int n  = j / 1824;
    int rj = j - n * 1824;
    int hh, icq, ww;
    if (rj < 928) {                                // rows 0 and 57
        hh = (rj / 464) * 57;
        int q = rj % 464;
        icq = q / PD;
        ww  = q - icq * PD;
    } else {                                       // cols 0 and 57, rows 1..56
        int q = rj - 928;                          // < 896
        hh = 1 + (q >> 4);
        int r2 = q & 15;
        icq = r2 >> 1;
        ww  = (r2 & 1) * 57;
    }
    size_t chunk = (((size_t)n * PD + hh) * NICQ + icq) * PD + ww;
    *(int4*)(apk8 + chunk * 16) = make_int4(0, 0, 0, 0);
}

// Kernel 1: SDP weight gen + binarize; int8 +-1 in MFMA B-fragment order.
__global__ void __launch_bounds__(256) wpack_kernel(
    const float* __restrict__ M, const float* __restrict__ Z,
    const float* __restrict__ rv, int8_t* __restrict__ bfrag) {
    int i = blockIdx.x * 256 + threadIdx.x;       // < 147456
    int oc = i / 1152;
    int r1 = i - oc * 1152;
    int ic = r1 / 9;
    int tap = r1 - ic * 9;

    float m  = M[i];
    float z0 = Z[0 * NWEL + i];
    float z1 = Z[1 * NWEL + i];
    float z2 = Z[2 * NWEL + i];
    float z3 = Z[3 * NWEL + i];
    float z4 = Z[4 * NWEL + i];
    float s  = z0 * z0 + z1 * z1 + z2 * z2 + z3 * z3 + z4 * z4;
    float A  = m * m + s * (1.0f / SCALE_F);
    float inv = 1.0f / sqrtf(A);
    float w = rv[0] * (z0 * inv);
    w += rv[1] * (z1 * inv);
    w += rv[2] * (z2 * inv);
    w += rv[3] * (z3 * inv);
    w += rv[4] * (z4 * inv);
    w += m * inv;

    int8_t sv = (w > 0.0f) ? (int8_t)1 : (int8_t)-1;
    int icb = ic >> 5, khalf = (ic >> 4) & 1, b = ic & 15;
    int kk  = icb * 9 + tap;                      // K order matches bconv
    int oct = oc >> 5;
    int lane = khalf * 32 + (oc & 31);
    bfrag[(size_t)((kk * 4 + oct) * 64 + lane) * 16 + b] = sv;
}

// Kernel 2: binarize f32 NCHW -> int8 chunked layout [n][hh][icq][ww][16].
__global__ void __launch_bounds__(448) apack_kernel(
    const float* __restrict__ x, int8_t* __restrict__ apk8) {
    int h = blockIdx.x;           // 0..55
    int n = blockIdx.y;           // 0..63
    int t = threadIdx.x;          // 0..447
    int w   = t % 56;
    int icq = t / 56;             // 0..7
    const float* xp = x + ((size_t)n * IC + icq * 16) * HWSZ + h * WW + w;

    uint32_t pk[4];
#pragma unroll
    for (int g = 0; g < 4; ++g) {
        uint32_t v = 0;
#pragma unroll
        for (int j = 0; j < 4; ++j) {
            float f = xp[(size_t)(g * 4 + j) * HWSZ];
            uint32_t sel = (f > 0.0f) ? 0x01u : 0xFFu;
            v |= sel << (8 * j);
        }
        pk[g] = v;
    }
    size_t chunk = (((size_t)n * PD + (h + 1)) * NICQ + icq) * PD + (w + 1);
    *(uint4*)(apk8 + chunk * 16) = make_uint4(pk[0], pk[1], pk[2], pk[3]);
}

// Kernel 3: implicit-GEMM conv via v_mfma_i32_32x32x32_i8 — ALL-LDS K-loop.
// grid = 896 (8 XCD x 112, bijective swizzle), block = 448 thr = 7 waves.
// Block = 8 full output rows x 56 cols (448 px, no dead lanes) x 64 oc.
// Stage ONCE: A-halo 10 padded rows (74.2 KB, contiguous) + B-half (72 KB)
// = 146.2 KB LDS, 1 block/CU. K-loop reads ONLY LDS, zero barriers, fully
// unrolled, 1-deep prefetch. Epilogue reuses ldsB after one barrier.
__global__ void __launch_bounds__(448) bconv_kernel(
    const int8_t* __restrict__ apk8, const int8_t* __restrict__ bfrag,
    const float* __restrict__ alpha, float* __restrict__ out) {
    __shared__ uint4 ldsA[4640];   // 74,240 B: [row10][icq8][ww58]
    __shared__ uint4 ldsB[4608];   // 73,728 B: [kk36][j2][lane64]

    int tx = threadIdx.x;
    int lane = tx & 63, wid = tx >> 6;
    int half = lane >> 5, l31 = lane & 31;

    int bid = blockIdx.x;
    int swz = (bid & 7) * 112 + (bid >> 3);   // bijective (896 = 8*112)
    int och = swz & 1;
    int rest = swz >> 1;                       // 0..447
    int n  = rest / 7;
    int hb = rest - n * 7;
    int h0 = hb * 8;
    int ocb = och * 64;

    // ---- stage A-halo: padded rows h0..h0+9, contiguous 4640 chunks ----
    const uint4* gA = (const uint4*)apk8 + (size_t)(n * PD + h0) * (NICQ * PD);
    for (int idx = tx; idx < 4640; idx += 448) ldsA[idx] = gA[idx];
    // ---- stage B-half: 4608 chunks ----
    const uint4* gB = (const uint4*)bfrag;
    for (int idx = tx; idx < 4608; idx += 448) {
        int kk = idx >> 7, j = (idx >> 6) & 1, ln = idx & 63;
        ldsB[idx] = gB[((kk << 2) + (och << 1) + j) * 64 + ln];
    }

    // per-lane px/addresses (div by 56 at setup only)
    int p0 = wid * 64 + l31;           // tm=0 px in block (0..447)
    int p1 = p0 + 32;
    int r0 = p0 / 56, c0 = p0 - r0 * 56;
    int r1 = p1 / 56, c1 = p1 - r1 * 56;
    int ab0 = ((r0 + 1) * NICQ + half) * PD + (c0 + 1);
    int ab1 = ((r1 + 1) * NICQ + half) * PD + (c1 + 1);
    size_t ob0 = ((size_t)n * OC + half) * HWSZ + (h0 * WW + p0);
    size_t ob1 = ((size_t)n * OC + half) * HWSZ + (h0 * WW + p1);

    __syncthreads();

    v16i acc[2][2] = {};
    v4i a0c = *(const v4i*)&ldsA[ab0 + koff2(0)];
    v4i a1c = *(const v4i*)&ldsA[ab1 + koff2(0)];
    v4i b0c = *(const v4i*)&ldsB[0 * 128 + lane];
    v4i b1c = *(const v4i*)&ldsB[0 * 128 + 64 + lane];

#pragma unroll
    for (int kk = 0; kk < 36; ++kk) {
        v4i a0n = a0c, a1n = a1c, b0n = b0c, b1n = b1c;
        if (kk < 35) {   // static after unroll: issue next-iter LDS reads early
            a0n = *(const v4i*)&ldsA[ab0 + koff2(kk + 1)];
            a1n = *(const v4i*)&ldsA[ab1 + koff2(kk + 1)];
            b0n = *(const v4i*)&ldsB[(kk + 1) * 128 + lane];
            b1n = *(const v4i*)&ldsB[(kk + 1) * 128 + 64 + lane];
        }
        acc[0][0] = __builtin_amdgcn_mfma_i32_32x32x32_i8(a0c, b0c, acc[0][0], 0, 0, 0);
        acc[0][1] = __builtin_amdgcn_mfma_i32_32x32x32_i8(a0c, b1c, acc[0][1], 0, 0, 0);
        acc[1][0] = __builtin_amdgcn_mfma_i32_32x32x32_i8(a1c, b0c, acc[1][0], 0, 0, 0);
        acc[1][1] = __builtin_amdgcn_mfma_i32_32x32x32_i8(a1c, b1c, acc[1][1], 0, 0, 0);
        a0c = a0n; a1c = a1n; b0c = b0n; b1c = b1n;
    }

    __syncthreads();   // ldsB no longer needed -> reuse as transpose scratch

    // ---- epilogue: alpha-scale + wave-private LDS transpose (validated) ----
    float* tlw = (float*)ldsB + wid * (32 * 33);   // 7 waves x 4224 B
    float alf[2];
    alf[0] = alpha[ocb + l31];
    alf[1] = alpha[ocb + 32 + l31];

    size_t ob[2] = {ob0, ob1};
#pragma unroll
    for (int tm = 0; tm < 2; ++tm) {
#pragma unroll
        for (int tn = 0; tn < 2; ++tn) {
            // C layout: col(oc)=lane&31, row(px)=(r&3)+8*(r>>2)+4*half
#pragma unroll
            for (int r = 0; r < 16; ++r) {
                int row = (r & 3) + 8 * (r >> 2) + 4 * half;
                tlw[row * 33 + l31] = (float)acc[tm][tn][r] * alf[tn];
            }
            // wave-synchronous transpose read: lane -> (px=l31, oc=2r+half)
#pragma unroll
            for (int r = 0; r < 16; ++r) {
                float v = tlw[l31 * 33 + 2 * r + half];
                int oc = ocb + tn * 32 + 2 * r;
                out[ob[tm] + (size_t)oc * HWSZ] = v;
            }
        }
    }
}

// ===========================================================================
// ================== bitplane fallback path (verified R5) ===================
// ===========================================================================

__global__ void __launch_bounds__(256) wpack32_kernel(
    const float* __restrict__ M, const float* __restrict__ Z,
    const float* __restrict__ rv, uint32_t* __restrict__ wpk32) {
    int gtid = blockIdx.x * blockDim.x + threadIdx.x;
    int lane = gtid & 63;
    int wid  = gtid >> 6;
    int oc   = wid / 18;
    int r    = wid - oc * 18;
    int tap  = r >> 1;
    int word = r & 1;
    int ic   = word * 64 + lane;
    int idx  = (oc * IC + ic) * NTAP + tap;

    float m  = M[idx];
    float z0 = Z[0 * NWEL + idx];
    float z1 = Z[1 * NWEL + idx];
    float z2 = Z[2 * NWEL + idx];
    float z3 = Z[3 * NWEL + idx];
    float z4 = Z[4 * NWEL + idx];
    float s  = z0 * z0 + z1 * z1 + z2 * z2 + z3 * z3 + z4 * z4;
    float A  = m * m + s * (1.0f / SCALE_F);
    float inv = 1.0f / sqrtf(A);
    float w = rv[0] * (z0 * inv);
    w += rv[1] * (z1 * inv);
    w += rv[2] * (z2 * inv);
    w += rv[3] * (z3 * inv);
    w += rv[4] * (z4 * inv);
    w += m * inv;

    unsigned long long b = __ballot(w > 0.0f);
    if (lane == 0) {
        uint64_t* wpk = (uint64_t*)wpk32;
        wpk[(oc * NTAP + tap) * 2 + word] = b;
    }
}

__global__ void __launch_bounds__(256) apack32_kernel(
    const float* __restrict__ x, uint32_t* __restrict__ apk32) {
    int q  = blockIdx.x * blockDim.x + threadIdx.x;
    int wd = blockIdx.y;
    int n  = q / HWSZ;
    int hw = q - n * HWSZ;
    int h  = hw / WW;
    int w  = hw - h * WW;
    const float* xp = x + (size_t)n * IC * HWSZ + (size_t)wd * 32 * HWSZ + hw;

    uint32_t b = 0;
#pragma unroll
    for (int c = 0; c < 32; ++c)
        b |= (uint32_t)(xp[(size_t)c * HWSZ] > 0.0f) << c;

    apk32[(size_t)wd * PLSTRIDE + (size_t)n * PLANE + (size_t)(h + 1) * PW + (w + 1)] = b;
}

__global__ void __launch_bounds__(256, 8) bconv32_kernel(
    const uint32_t* __restrict__ apk32, const uint32_t* __restrict__ wpk32,
    const float* __restrict__ alpha, float* __restrict__ out) {
    __shared__ int adj[OCPB][9];
    __shared__ float alf[OCPB];

    int tx  = threadIdx.x;
    int oc0 = blockIdx.y * OCPB;

    if (tx < OCPB) alf[tx] = alpha[oc0 + tx];
    if (tx < OCPB * 9) {
        int ocl = tx / 9, cls = tx % 9;
        int rc = cls / 3, cc = cls % 3;
        int nv = ((rc == 1) ? 3 : 2) * ((cc == 1) ? 3 : 2);
        int s = 0;
#pragma unroll
        for (int t = 0; t < NTAP; ++t) {
            int i = t / 3, j = t % 3;
            bool invld = (rc == 0 && i == 0) || (rc == 2 && i == 2) ||
                         (cc == 0 && j == 0) || (cc == 2 && j == 2);
            if (invld) {
                const uint64_t* wpk = (const uint64_t*)wpk32;
                uint64_t lo = wpk[(oc0 + ocl) * NTAP * 2 + t * 2 + 0];
                uint64_t hi = wpk[(oc0 + ocl) * NTAP * 2 + t * 2 + 1];
                s += __popcll(lo) + __popcll(hi);
            }
        }
        adj[ocl][cls] = 128 * nv + 2 * s;
    }
    __syncthreads();

    int t  = blockIdx.x * blockDim.x + tx;
    int sw = t % 14;
    int h  = (t / 14) % HH;
    int n  = t / (14 * HH);
    int w0 = sw * WPT;

    const uint32_t* ap = apk32 + (size_t)n * PLANE + (size_t)h * PW + w0;
    const uint64_t* wpk = (const uint64_t*)wpk32;

    int cnt[WPT * OCPB] = {0};
#pragma unroll 1
    for (int r = 0; r < 3; ++r) {
#pragma unroll 1
        for (int wd = 0; wd < 4; ++wd) {
            const uint32_t* p = ap + (size_t)wd * PLSTRIDE + (size_t)r * PW;
            uint32_t T[6];
#pragma unroll
            for (int c = 0; c < 6; ++c) T[c] = p[c];
#pragma unroll
            for (int j = 0; j < 3; ++j) {
#pragma unroll
                for (int ocl = 0; ocl < OCPB; ++ocl) {
                    uint64_t w2 = wpk[(oc0 + ocl) * NTAP * 2 + (r * 3 + j) * 2 + (wd >> 1)];
                    uint32_t wv = (wd & 1) ? (uint32_t)(w2 >> 32) : (uint32_t)w2;
#pragma unroll
                    for (int o = 0; o < WPT; ++o)
                        cnt[o * OCPB + ocl] += __popc(T[j + o] ^ wv);
                }
            }
        }
    }

    int rcls = (h == 0) ? 0 : ((h == HH - 1) ? 6 : 3);
    int clsL = rcls + ((w0 == 0) ? 0 : 1);
    int clsI = rcls + 1;
    int clsR = rcls + ((w0 == WW - WPT) ? 2 : 1);
    float* op = out + ((size_t)n * OC + oc0) * HWSZ + h * WW + w0;
#pragma unroll
    for (int ocl = 0; ocl < OCPB; ++ocl) {
        float a = alf[ocl];
        float4 v;
        v.x = (float)(adj[ocl][clsL] - 2 * cnt[0 * OCPB + ocl]) * a;
        v.y = (float)(adj[ocl][clsI] - 2 * cnt[1 * OCPB + ocl]) * a;
        v.z = (float)(adj[ocl][clsI] - 2 * cnt[2 * OCPB + ocl]) * a;
        v.w = (float)(adj[ocl][clsR] - 2 * cnt[3 * OCPB + ocl]) * a;
        *(float4*)(op + (size_t)ocl * HWSZ) = v;
    }
}

extern "C" void kernel_launch(void* const* d_in, const int* in_sizes, int n_in,
                              void* d_out, int out_size, void* d_ws, size_t ws_size,
                              hipStream_t stream) {
    const float* x     = (const float*)d_in[0];
    const float* M     = (const float*)d_in[1];
    const float* Z     = (const float*)d_in[2];
    const float* Alpha = (const float*)d_in[3];
    const float* rv    = (const float*)d_in[4];
    float* out = (float*)d_out;

    const size_t mfma_needed = 196608 + (size_t)NB * PD * NICQ * PD * 16;  // ~27.8 MB

    if (ws_size >= mfma_needed) {
        int8_t* bfrag = (int8_t*)d_ws;                      // 147,456 B
        int8_t* apk8  = (int8_t*)d_ws + 196608;             // 27,557,888 B

        border_kernel<<<(NB * 1824) / 256, 256, 0, stream>>>(apk8);
        wpack_kernel<<<NWEL / 256, 256, 0, stream>>>(M, Z, rv, bfrag);
        apack_kernel<<<dim3(HH, NB), 448, 0, stream>>>(x, apk8);
        bconv_kernel<<<896, 448, 0, stream>>>(apk8, bfrag, Alpha, out);
    } else {
        // verified bitplane fallback (R5)
        uint32_t* wpk32 = (uint32_t*)d_ws;                  // 18,432 B
        uint32_t* apk32 = (uint32_t*)((char*)d_ws + 32768); // 3,563,520 B

        hipMemsetAsync(apk32, 0, (size_t)4 * PLSTRIDE * 4, stream);
        wpack32_kernel<<<NWEL / 256, 256, 0, stream>>>(M, Z, rv, wpk32);
        apack32_kernel<<<dim3((NB * HWSZ) / 256, 4), 256, 0, stream>>>(x, apk32);
        bconv32_kernel<<<dim3((NB * HH * 14) / 256, OC / OCPB), 256, 0, stream>>>(
            apk32, wpk32, Alpha, out);
    }
}

// Round 16
// 81.210 us; speedup vs baseline: 1.1669x; 1.1669x over previous
//
#include <hip/hip_runtime.h>
#include <stdint.h>

#define KK 5
#define SCALE_F 50000.0f
#define OC 128
#define IC 128
#define HH 56
#define WW 56
#define NB 64
#define HWSZ (HH * WW)          // 3136
#define NTAP 9
#define NWEL (OC * IC * NTAP)   // 147456

// ---- MFMA path geometry ----
#define PD 58                   // padded spatial dim
#define NICQ 8                  // 16-byte ic-chunks per pixel (128 ic)
// apk8 chunk index: ((n*PD + hh)*NICQ + icq)*PD + ww ; byte addr = chunk*16
// bfrag chunk index: (kk*4 + oct)*64 + lane   (kk = icb*9 + tap)

// ---- bitplane fallback geometry (verified R5) ----
#define PW 60
#define PROWS 58
#define PLANE (PROWS * PW)      // 3480
#define PLSTRIDE (NB * PLANE)   // 222720
#define OCPB 2
#define WPT 4

typedef int v4i  __attribute__((ext_vector_type(4)));
typedef int v16i __attribute__((ext_vector_type(16)));

__device__ __forceinline__ constexpr int koff2(int kk) {
    int icb = kk / 9, tap = kk % 9;
    int dh = tap / 3 - 1, dw = tap % 3 - 1;
    return (dh * NICQ + icb * 2) * PD + dw;
}

// ===========================================================================
// ============================ MFMA (primary) path ==========================
// ===========================================================================

// Kernel 0: zero the padded borders of apk8 (1824 chunks per n).
__global__ void __launch_bounds__(256) border_kernel(int8_t* __restrict__ apk8) {
    int j = blockIdx.x * 256 + threadIdx.x;       // < 64*1824 = 116736
    int n  = j / 1824;
    int rj = j - n * 1824;
    int hh, icq, ww;
    if (rj < 928) {                                // rows 0 and 57
        hh = (rj / 464) * 57;
        int q = rj % 464;
        icq = q / PD;
        ww  = q - icq * PD;
    } else {                                       // cols 0 and 57, rows 1..56
        int q = rj - 928;                          // < 896
        hh = 1 + (q >> 4);
        int r2 = q & 15;
        icq = r2 >> 1;
        ww  = (r2 & 1) * 57;
    }
    size_t chunk = (((size_t)n * PD + hh) * NICQ + icq) * PD + ww;
    *(int4*)(apk8 + chunk * 16) = make_int4(0, 0, 0, 0);
}

// Kernel 1: SDP weight gen + binarize; int8 +-1 in MFMA B-fragment order.
__global__ void __launch_bounds__(256) wpack_kernel(
    const float* __restrict__ M, const float* __restrict__ Z,
    const float* __restrict__ rv, int8_t* __restrict__ bfrag) {
    int i = blockIdx.x * 256 + threadIdx.x;       // < 147456
    int oc = i / 1152;
    int r1 = i - oc * 1152;
    int ic = r1 / 9;
    int tap = r1 - ic * 9;

    float m  = M[i];
    float z0 = Z[0 * NWEL + i];
    float z1 = Z[1 * NWEL + i];
    float z2 = Z[2 * NWEL + i];
    float z3 = Z[3 * NWEL + i];
    float z4 = Z[4 * NWEL + i];
    float s  = z0 * z0 + z1 * z1 + z2 * z2 + z3 * z3 + z4 * z4;
    float A  = m * m + s * (1.0f / SCALE_F);
    float inv = 1.0f / sqrtf(A);
    float w = rv[0] * (z0 * inv);
    w += rv[1] * (z1 * inv);
    w += rv[2] * (z2 * inv);
    w += rv[3] * (z3 * inv);
    w += rv[4] * (z4 * inv);
    w += m * inv;

    int8_t sv = (w > 0.0f) ? (int8_t)1 : (int8_t)-1;
    int icb = ic >> 5, khalf = (ic >> 4) & 1, b = ic & 15;
    int kk  = icb * 9 + tap;                      // K order matches bconv
    int oct = oc >> 5;
    int lane = khalf * 32 + (oc & 31);
    bfrag[(size_t)((kk * 4 + oct) * 64 + lane) * 16 + b] = sv;
}

// Kernel 2: binarize f32 NCHW -> int8 chunked layout [n][hh][icq][ww][16].
__global__ void __launch_bounds__(448) apack_kernel(
    const float* __restrict__ x, int8_t* __restrict__ apk8) {
    int h = blockIdx.x;           // 0..55
    int n = blockIdx.y;           // 0..63
    int t = threadIdx.x;          // 0..447
    int w   = t % 56;
    int icq = t / 56;             // 0..7
    const float* xp = x + ((size_t)n * IC + icq * 16) * HWSZ + h * WW + w;

    uint32_t pk[4];
#pragma unroll
    for (int g = 0; g < 4; ++g) {
        uint32_t v = 0;
#pragma unroll
        for (int j = 0; j < 4; ++j) {
            float f = xp[(size_t)(g * 4 + j) * HWSZ];
            uint32_t sel = (f > 0.0f) ? 0x01u : 0xFFu;
            v |= sel << (8 * j);
        }
        pk[g] = v;
    }
    size_t chunk = (((size_t)n * PD + (h + 1)) * NICQ + icq) * PD + (w + 1);
    *(uint4*)(apk8 + chunk * 16) = make_uint4(pk[0], pk[1], pk[2], pk[3]);
}

// Kernel 3: implicit-GEMM conv via v_mfma_i32_32x32x32_i8.
// Block = 768 thr = 12 waves; wave = 32 px x 64 oc ([1 px-tile][2 oc-tiles],
// acc = 32 regs). A reused across both oc tiles -> 0.5 A-loads/MFMA (L1);
// B-half (72 KB) in LDS -> 2 blocks/CU x 12 waves = 24 waves/CU (6/SIMD,
// reg cap 85 via launch_bounds(768,6)). K-loop: zero barriers, full unroll,
// A ring-4 (3 ahead) + B ring-2 prefetch, all indices compile-time.
// grid = 1046 (523 px-blocks x 2 oc-halves; last px-block partial, stores
// guarded; OOB A-reads land inside d_ws -> safe garbage).
__global__ void __launch_bounds__(768, 6) bconv_kernel(
    const int8_t* __restrict__ apk8, const int8_t* __restrict__ bfrag,
    const float* __restrict__ alpha, float* __restrict__ out) {
    __shared__ uint4 ldsB[4608];   // [kk36][j2][lane64], 73,728 B

    int tx = threadIdx.x;
    int lane = tx & 63, wid = tx >> 6;        // wid 0..11
    int half = lane >> 5, l31 = lane & 31;

    // m204 bijective XCD swizzle: nwg=1046, q=130, r=6
    int bid = blockIdx.x;
    int xcd = bid & 7, pos = bid >> 3;
    int base = (xcd < 6) ? xcd * 131 : (6 * 131 + (xcd - 6) * 130);
    int swz = base + pos;                      // 0..1045
    int och = swz & 1;                         // oc half (paired per XCD)
    int pxb = swz >> 1;                        // 0..522
    int ocb = och * 64;

    // ---- stage B-half once: 4608 chunks, 6 per thread, coalesced ----
    const uint4* gB = (const uint4*)bfrag;
#pragma unroll
    for (int s = 0; s < 6; ++s) {
        int idx = tx + s * 768;
        int kk = idx >> 7, j = (idx >> 6) & 1, ln = idx & 63;
        ldsB[idx] = gB[((kk << 2) + (och << 1) + j) * 64 + ln];
    }

    int px = pxb * 384 + wid * 32 + l31;       // may exceed 200703 (guarded)
    int n  = px / HWSZ;
    int hw = px - n * HWSZ;
    int h  = hw / WW;
    int w  = hw - h * WW;
    int ab0 = ((n * PD + h + 1) * NICQ + half) * PD + (w + 1);
    size_t ob0 = ((size_t)n * OC + half) * HWSZ + hw;
    bool valid = (px < NB * HWSZ);

    __syncthreads();

    v16i acc0 = {}, acc1 = {};
    // A ring-4: preload kk = 0,1,2
    v4i a0 = *(const v4i*)(apk8 + ((size_t)(ab0 + koff2(0)) << 4));
    v4i a1 = *(const v4i*)(apk8 + ((size_t)(ab0 + koff2(1)) << 4));
    v4i a2 = *(const v4i*)(apk8 + ((size_t)(ab0 + koff2(2)) << 4));
    v4i a3;
    // B ring-2: preload kk = 0
    v4i b0c = *(const v4i*)&ldsB[0 * 128 + lane];
    v4i b1c = *(const v4i*)&ldsB[0 * 128 + 64 + lane];
    v4i b0n, b1n;

#pragma unroll
    for (int kk = 0; kk < 36; ++kk) {
        // select current A from ring (compile-time after unroll)
        v4i A = (kk & 3) == 0 ? a0 : ((kk & 3) == 1 ? a1 : ((kk & 3) == 2 ? a2 : a3));
        // prefetch A kk+3
        if (kk + 3 < 36) {
            v4i t = *(const v4i*)(apk8 + ((size_t)(ab0 + koff2(kk + 3)) << 4));
            switch ((kk + 3) & 3) {
                case 0: a0 = t; break;
                case 1: a1 = t; break;
                case 2: a2 = t; break;
                default: a3 = t; break;
            }
        }
        // prefetch B kk+1
        if (kk + 1 < 36) {
            b0n = *(const v4i*)&ldsB[(kk + 1) * 128 + lane];
            b1n = *(const v4i*)&ldsB[(kk + 1) * 128 + 64 + lane];
        }
        acc0 = __builtin_amdgcn_mfma_i32_32x32x32_i8(A, b0c, acc0, 0, 0, 0);
        acc1 = __builtin_amdgcn_mfma_i32_32x32x32_i8(A, b1c, acc1, 0, 0, 0);
        b0c = b0n; b1c = b1n;
    }

    __syncthreads();   // ldsB free -> reuse as transpose scratch

    // ---- epilogue: alpha-scale + wave-private LDS transpose (validated) ----
    float* tlw = (float*)ldsB + wid * (32 * 33);   // 12 waves x 4224 B = 50.7 KB
    float alf[2];
    alf[0] = alpha[ocb + l31];
    alf[1] = alpha[ocb + 32 + l31];

#pragma unroll
    for (int tn = 0; tn < 2; ++tn) {
        const v16i* ac = tn ? &acc1 : &acc0;
        // C layout: col(oc)=lane&31, row(px)=(r&3)+8*(r>>2)+4*half
#pragma unroll
        for (int r = 0; r < 16; ++r) {
            int row = (r & 3) + 8 * (r >> 2) + 4 * half;
            tlw[row * 33 + l31] = (float)(*ac)[r] * alf[tn];
        }
        // wave-synchronous transpose read: lane -> (px=l31, oc=2r+half)
        if (valid) {
#pragma unroll
            for (int r = 0; r < 16; ++r) {
                float v = tlw[l31 * 33 + 2 * r + half];
                int oc = ocb + tn * 32 + 2 * r;
                out[ob0 + (size_t)oc * HWSZ] = v;
            }
        }
    }
}

// ===========================================================================
// ================== bitplane fallback path (verified R5) ===================
// ===========================================================================

__global__ void __launch_bounds__(256) wpack32_kernel(
    const float* __restrict__ M, const float* __restrict__ Z,
    const float* __restrict__ rv, uint32_t* __restrict__ wpk32) {
    int gtid = blockIdx.x * blockDim.x + threadIdx.x;
    int lane = gtid & 63;
    int wid  = gtid >> 6;
    int oc   = wid / 18;
    int r    = wid - oc * 18;
    int tap  = r >> 1;
    int word = r & 1;
    int ic   = word * 64 + lane;
    int idx  = (oc * IC + ic) * NTAP + tap;

    float m  = M[idx];
    float z0 = Z[0 * NWEL + idx];
    float z1 = Z[1 * NWEL + idx];
    float z2 = Z[2 * NWEL + idx];
    float z3 = Z[3 * NWEL + idx];
    float z4 = Z[4 * NWEL + idx];
    float s  = z0 * z0 + z1 * z1 + z2 * z2 + z3 * z3 + z4 * z4;
    float A  = m * m + s * (1.0f / SCALE_F);
    float inv = 1.0f / sqrtf(A);
    float w = rv[0] * (z0 * inv);
    w += rv[1] * (z1 * inv);
    w += rv[2] * (z2 * inv);
    w += rv[3] * (z3 * inv);
    w += rv[4] * (z4 * inv);
    w += m * inv;

    unsigned long long b = __ballot(w > 0.0f);
    if (lane == 0) {
        uint64_t* wpk = (uint64_t*)wpk32;
        wpk[(oc * NTAP + tap) * 2 + word] = b;
    }
}

__global__ void __launch_bounds__(256) apack32_kernel(
    const float* __restrict__ x, uint32_t* __restrict__ apk32) {
    int q  = blockIdx.x * blockDim.x + threadIdx.x;
    int wd = blockIdx.y;
    int n  = q / HWSZ;
    int hw = q - n * HWSZ;
    int h  = hw / WW;
    int w  = hw - h * WW;
    const float* xp = x + (size_t)n * IC * HWSZ + (size_t)wd * 32 * HWSZ + hw;

    uint32_t b = 0;
#pragma unroll
    for (int c = 0; c < 32; ++c)
        b |= (uint32_t)(xp[(size_t)c * HWSZ] > 0.0f) << c;

    apk32[(size_t)wd * PLSTRIDE + (size_t)n * PLANE + (size_t)(h + 1) * PW + (w + 1)] = b;
}

__global__ void __launch_bounds__(256, 8) bconv32_kernel(
    const uint32_t* __restrict__ apk32, const uint32_t* __restrict__ wpk32,
    const float* __restrict__ alpha, float* __restrict__ out) {
    __shared__ int adj[OCPB][9];
    __shared__ float alf[OCPB];

    int tx  = threadIdx.x;
    int oc0 = blockIdx.y * OCPB;

    if (tx < OCPB) alf[tx] = alpha[oc0 + tx];
    if (tx < OCPB * 9) {
        int ocl = tx / 9, cls = tx % 9;
        int rc = cls / 3, cc = cls % 3;
        int nv = ((rc == 1) ? 3 : 2) * ((cc == 1) ? 3 : 2);
        int s = 0;
#pragma unroll
        for (int t = 0; t < NTAP; ++t) {
            int i = t / 3, j = t % 3;
            bool invld = (rc == 0 && i == 0) || (rc == 2 && i == 2) ||
                         (cc == 0 && j == 0) || (cc == 2 && j == 2);
            if (invld) {
                const uint64_t* wpk = (const uint64_t*)wpk32;
                uint64_t lo = wpk[(oc0 + ocl) * NTAP * 2 + t * 2 + 0];
                uint64_t hi = wpk[(oc0 + ocl) * NTAP * 2 + t * 2 + 1];
                s += __popcll(lo) + __popcll(hi);
            }
        }
        adj[ocl][cls] = 128 * nv + 2 * s;
    }
    __syncthreads();

    int t  = blockIdx.x * blockDim.x + tx;
    int sw = t % 14;
    int h  = (t / 14) % HH;
    int n  = t / (14 * HH);
    int w0 = sw * WPT;

    const uint32_t* ap = apk32 + (size_t)n * PLANE + (size_t)h * PW + w0;
    const uint64_t* wpk = (const uint64_t*)wpk32;

    int cnt[WPT * OCPB] = {0};
#pragma unroll 1
    for (int r = 0; r < 3; ++r) {
#pragma unroll 1
        for (int wd = 0; wd < 4; ++wd) {
            const uint32_t* p = ap + (size_t)wd * PLSTRIDE + (size_t)r * PW;
            uint32_t T[6];
#pragma unroll
            for (int c = 0; c < 6; ++c) T[c] = p[c];
#pragma unroll
            for (int j = 0; j < 3; ++j) {
#pragma unroll
                for (int ocl = 0; ocl < OCPB; ++ocl) {
                    uint64_t w2 = wpk[(oc0 + ocl) * NTAP * 2 + (r * 3 + j) * 2 + (wd >> 1)];
                    uint32_t wv = (wd & 1) ? (uint32_t)(w2 >> 32) : (uint32_t)w2;
#pragma unroll
                    for (int o = 0; o < WPT; ++o)
                        cnt[o * OCPB + ocl] += __popc(T[j + o] ^ wv);
                }
            }
        }
    }

    int rcls = (h == 0) ? 0 : ((h == HH - 1) ? 6 : 3);
    int clsL = rcls + ((w0 == 0) ? 0 : 1);
    int clsI = rcls + 1;
    int clsR = rcls + ((w0 == WW - WPT) ? 2 : 1);
    float* op = out + ((size_t)n * OC + oc0) * HWSZ + h * WW + w0;
#pragma unroll
    for (int ocl = 0; ocl < OCPB; ++ocl) {
        float a = alf[ocl];
        float4 v;
        v.x = (float)(adj[ocl][clsL] - 2 * cnt[0 * OCPB + ocl]) * a;
        v.y = (float)(adj[ocl][clsI] - 2 * cnt[1 * OCPB + ocl]) * a;
        v.z = (float)(adj[ocl][clsI] - 2 * cnt[2 * OCPB + ocl]) * a;
        v.w = (float)(adj[ocl][clsR] - 2 * cnt[3 * OCPB + ocl]) * a;
        *(float4*)(op + (size_t)ocl * HWSZ) = v;
    }
}

extern "C" void kernel_launch(void* const* d_in, const int* in_sizes, int n_in,
                              void* d_out, int out_size, void* d_ws, size_t ws_size,
                              hipStream_t stream) {
    const float* x     = (const float*)d_in[0];
    const float* M     = (const float*)d_in[1];
    const float* Z     = (const float*)d_in[2];
    const float* Alpha = (const float*)d_in[3];
    const float* rv    = (const float*)d_in[4];
    float* out = (float*)d_out;

    // MFMA path needs apk8 (27.5 MB) + slack for OOB reads from the padded
    // grid (last partial px-block reads < 0.25 MB past apk8 end).
    const size_t mfma_needed = 196608 + (size_t)NB * PD * NICQ * PD * 16 + (1 << 20);

    if (ws_size >= mfma_needed) {
        int8_t* bfrag = (int8_t*)d_ws;                      // 147,456 B
        int8_t* apk8  = (int8_t*)d_ws + 196608;             // 27,557,888 B

        border_kernel<<<(NB * 1824) / 256, 256, 0, stream>>>(apk8);
        wpack_kernel<<<NWEL / 256, 256, 0, stream>>>(M, Z, rv, bfrag);
        apack_kernel<<<dim3(HH, NB), 448, 0, stream>>>(x, apk8);
        bconv_kernel<<<1046, 768, 0, stream>>>(apk8, bfrag, Alpha, out);
    } else {
        // verified bitplane fallback (R5)
        uint32_t* wpk32 = (uint32_t*)d_ws;                  // 18,432 B
        uint32_t* apk32 = (uint32_t*)((char*)d_ws + 32768); // 3,563,520 B

        hipMemsetAsync(apk32, 0, (size_t)4 * PLSTRIDE * 4, stream);
        wpack32_kernel<<<NWEL / 256, 256, 0, stream>>>(M, Z, rv, wpk32);
        apack32_kernel<<<dim3((NB * HWSZ) / 256, 4), 256, 0, stream>>>(x, apk32);
        bconv32_kernel<<<dim3((NB * HH * 14) / 256, OC / OCPB), 256, 0, stream>>>(
            apk32, wpk32, Alpha, out);
    }
}